// Round 13
// baseline (70.202 us; speedup 1.0000x reference)
//
#include <hip/hip_runtime.h>
#include <hip/hip_bf16.h>
#include <stdint.h>

#define EMBED 128
#define HID 145
#define HSTR 160            // padded col count per table (MFMA tiles)
#define NTILE 20            // 320 output cols / 16
#define KCH 4               // 128 K / 32
#define MROWB 128           // int6 row: 29 u32 packed vals (cols 0..144) + f32 scale @ u32 29
#define LROW 152            // LDS staging row stride: 145 bytes + 3 pad + f32 scale @ 148
#define HB2ROW 272          // bf16 h-staging row stride in bytes (256 + 16 pad)

typedef __attribute__((ext_vector_type(8))) short short8;
typedef __attribute__((ext_vector_type(4))) float f32x4;

__device__ __forceinline__ uint16_t f2bf(float f) {
    uint32_t x = __float_as_uint(f);
    x += 0x7FFFu + ((x >> 16) & 1u);          // round-to-nearest-even
    return (uint16_t)(x >> 16);
}
__device__ __forceinline__ short f2bf_cvt(float f) {
    union { __bf16 h; short s; } u_;
    u_.h = (__bf16)f;
    return u_.s;
}

// ---------------------------------------------------------------------------
// prep_fused: blocks [0,P): pack pairs[e]=(src<<16)|dst
//             blocks [P,P+160): pack W1 into bf16 B-fragment order (Wpb)
//             block P+160: fold cancer/b1/causal cols; plain zero-padded W2
// ---------------------------------------------------------------------------
__global__ void __launch_bounds__(256)
prep_fused(const float* __restrict__ cancer, const float* __restrict__ W1,
           const float* __restrict__ b1, const float* __restrict__ W2,
           const void* __restrict__ eiv, int E, int P,
           float* __restrict__ b1p, float* __restrict__ wci,
           float* __restrict__ wcj, float* __restrict__ w2p,
           short* __restrict__ Wpb, uint32_t* __restrict__ pairs)
{
    const int t = threadIdx.x;
    const int b = blockIdx.x;
    if (b < P) {
        // int64 indices < 65536 => every odd 32-bit word is zero.
        const uint32_t* pw = (const uint32_t*)eiv;
        const uint32_t odd = pw[1] | pw[3] | pw[5] | pw[7] | pw[9] | pw[11] | pw[13] | pw[15];
        const int is64 = (odd == 0u);
        const int e = b * 256 + t;
        if (e < E) {
            uint32_t src, dst;
            if (is64) {
                const long long* e64 = (const long long*)eiv;
                src = (uint32_t)e64[e]; dst = (uint32_t)e64[(size_t)E + e];
            } else {
                const uint32_t* e32 = (const uint32_t*)eiv;
                src = e32[e];           dst = e32[(size_t)E + e];
            }
            pairs[e] = (src << 16) | (dst & 0xFFFFu);
        }
        return;
    }
    if (b < P + 160) {
        const int idx = (b - P) * 256 + t;            // < 40960
        const int reg  = idx & 7;
        const int lane = (idx >> 3) & 63;
        const int tl   = idx >> 9;                    // 0..79
        const int tt   = tl % NTILE;
        const int kc   = tl / NTILE;
        const int k    = kc * 32 + (lane >> 4) * 8 + reg;
        const int col  = tt * 16 + (lane & 15);
        float val = 0.f;
        if (col < HID)                             val = W1[(size_t)k * HID + col];
        else if (col >= HSTR && col < HSTR + HID)  val = W1[(size_t)(EMBED + k) * HID + (col - HSTR)];
        Wpb[idx] = (short)f2bf(val);
        return;
    }
    // smalls
    if (t < HSTR) {
        float bv = 0.f, a = 0.f, bb = 0.f, w2 = 0.f;
        if (t < HID) {
            float s = b1[t];
            #pragma unroll
            for (int k = 0; k < 32; ++k)
                s = fmaf(cancer[k], W1[(size_t)(2 * EMBED + k) * HID + t], s);
            bv = s;
            a  = W1[(size_t)288 * HID + t] + W1[(size_t)290 * HID + t];  // c_i + diff
            bb = W1[(size_t)289 * HID + t] - W1[(size_t)290 * HID + t];  // c_j - diff
            w2 = W2[t];
        }
        b1p[t] = bv; wci[t] = a; wcj[t] = bb; w2p[t] = w2;   // plain col order
    }
}

// ---------------------------------------------------------------------------
// proj_mfma (r11 structure, measured best): 64 nodes/block, wave w owns
//   5 tiles [5w,5w+5) x all 64 nodes (4 groups). Per kc: 5 B-fragment loads
//   reused across 4 groups; A via ds_read_b128 from bf16-staged h.
// ---------------------------------------------------------------------------
__global__ void __launch_bounds__(256)
proj_mfma(const float* __restrict__ h, const short* __restrict__ Wpb,
          const float* __restrict__ causal, const float* __restrict__ b1p,
          const float* __restrict__ wci, const float* __restrict__ wcj,
          uint8_t* __restrict__ u, uint8_t* __restrict__ v, int nNodes)
{
    __shared__ __align__(16) uint8_t smem[2 * 64 * LROW];   // 19456 B (>= 64*HB2ROW)
    __shared__ float pmax[2][2][64];                        // [table][wave-half][row]

    const int t = threadIdx.x;
    const int lane = t & 63;
    const int w = t >> 6;
    const int lane15 = lane & 15, hi = lane >> 4;
    const int n0blk = blockIdx.x * 64;
    const bool full = (n0blk + 64 <= nNodes);

    // ---- stage h as bf16: 64 rows x 256 B, dense coalesced copies
    const float4* hsrc = (const float4*)(h + (size_t)n0blk * EMBED);
    if (full) {
        #pragma unroll
        for (int k = 0; k < 8; ++k) {
            const int f = k * 256 + t;                 // float4 idx 0..2047
            const float4 x = hsrc[f];
            const uint32_t lo = (uint32_t)(uint16_t)f2bf_cvt(x.x)
                              | ((uint32_t)(uint16_t)f2bf_cvt(x.y) << 16);
            const uint32_t hg = (uint32_t)(uint16_t)f2bf_cvt(x.z)
                              | ((uint32_t)(uint16_t)f2bf_cvt(x.w) << 16);
            *(uint2*)(smem + (f >> 5) * HB2ROW + (f & 31) * 8) = make_uint2(lo, hg);
        }
    } else {
        #pragma unroll
        for (int k = 0; k < 8; ++k) {
            const int f = k * 256 + t;
            const int row = f >> 5;
            float4 x = make_float4(0.f, 0.f, 0.f, 0.f);
            if (n0blk + row < nNodes) x = hsrc[f];
            const uint32_t lo = (uint32_t)(uint16_t)f2bf_cvt(x.x)
                              | ((uint32_t)(uint16_t)f2bf_cvt(x.y) << 16);
            const uint32_t hg = (uint32_t)(uint16_t)f2bf_cvt(x.z)
                              | ((uint32_t)(uint16_t)f2bf_cvt(x.w) << 16);
            *(uint2*)(smem + row * HB2ROW + (f & 31) * 8) = make_uint2(lo, hg);
        }
    }
    __syncthreads();

    // ---- MFMA: acc[group g][tile i], tile tt = 5w+i, nodes g*16+row-in-frag
    const int w5 = 5 * w;
    const uint8_t* habase = smem + lane15 * HB2ROW + hi * 16;

    f32x4 acc[4][5];
    #pragma unroll
    for (int g = 0; g < 4; ++g)
        #pragma unroll
        for (int i = 0; i < 5; ++i) acc[g][i] = (f32x4){0.f, 0.f, 0.f, 0.f};

    const short8* bp = (const short8*)Wpb;
    #pragma unroll
    for (int kc = 0; kc < KCH; ++kc) {
        short8 bfr[5];
        #pragma unroll
        for (int i = 0; i < 5; ++i)
            bfr[i] = bp[(kc * NTILE + w5 + i) * 64 + lane];
        #pragma unroll
        for (int g = 0; g < 4; ++g) {
            const short8 a = *(const short8*)(habase + g * 16 * HB2ROW + kc * 64);
            #pragma unroll
            for (int i = 0; i < 5; ++i)
                acc[g][i] = __builtin_amdgcn_mfma_f32_16x16x32_bf16(a, bfr[i], acc[g][i], 0, 0, 0);
        }
    }

    // ---- fold bias/causal terms (addB/addC hoisted per tile)
    const int tb = w >> 1, hf = w & 1;                  // table (0=u,1=v), half
    float addB[5], addC[5];
    #pragma unroll
    for (int i = 0; i < 5; ++i) {
        const int col = (w5 + i) * 16 + lane15;
        const int ccol = tb ? col - HSTR : col;
        addB[i] = tb ? 0.f : b1p[ccol];
        addC[i] = tb ? wcj[ccol] : wci[ccol];
    }
    #pragma unroll
    for (int g = 0; g < 4; ++g) {
        float cz[4];
        #pragma unroll
        for (int j = 0; j < 4; ++j) {
            const int n = n0blk + g * 16 + hi * 4 + j;
            cz[j] = (n < nNodes) ? causal[n] : 0.f;
        }
        #pragma unroll
        for (int i = 0; i < 5; ++i)
            #pragma unroll
            for (int j = 0; j < 4; ++j)
                acc[g][i][j] += fmaf(cz[j], addC[i], addB[i]);
    }

    // ---- partial per-row absmax over this wave's 5 tiles -> pmax
    #pragma unroll
    for (int g = 0; g < 4; ++g) {
        #pragma unroll
        for (int j = 0; j < 4; ++j) {
            float m = fmaxf(fmaxf(fmaxf(fabsf(acc[g][0][j]), fabsf(acc[g][1][j])),
                                  fmaxf(fabsf(acc[g][2][j]), fabsf(acc[g][3][j]))),
                            fabsf(acc[g][4][j]));
            #pragma unroll
            for (int mk = 1; mk < 16; mk <<= 1) m = fmaxf(m, __shfl_xor(m, mk));
            if (lane15 == 0) pmax[tb][hf][g * 16 + hi * 4 + j] = m;
        }
    }
    __syncthreads();   // pmax complete; all h ds_reads done -> smem reusable

    // ---- quantize + LDS byte staging (disjoint col ranges per wave)
    uint8_t* ldsu = smem;
    uint8_t* ldsv = smem + 64 * LROW;
    uint8_t* myt = tb ? ldsv : ldsu;
    #pragma unroll
    for (int g = 0; g < 4; ++g) {
        #pragma unroll
        for (int j = 0; j < 4; ++j) {
            const int row = g * 16 + hi * 4 + j;
            const float mm = fmaxf(fmaxf(pmax[tb][0][row], pmax[tb][1][row]), 1e-20f);
            const float inv = 31.f / mm;
            if (hf == 0 && lane15 == 0)
                *(float*)(myt + row * LROW + 148) = mm * (1.f / 31.f);
            #pragma unroll
            for (int i = 0; i < 5; ++i) {
                const int ccol = (w5 + i) * 16 + lane15 - (tb ? HSTR : 0);
                const uint8_t q = (uint8_t)(uint32_t)(acc[g][i][j] * inv + 32.5f);
                if (ccol < 145)                      // skips pad lanes of tiles 9/19
                    myt[row * LROW + ccol] = q;
            }
        }
    }
    __syncthreads();

    // ---- repack + coalesced copy-out: idx in [0,512): row=idx>>3, chunk c=idx&7
    // chunk c<7: u32s 4c..4c+3 = cols 20c..20c+19; c==7: vals 140-144 + scale
    char* ug = (char*)u + (size_t)n0blk * MROWB;
    char* vg = (char*)v + (size_t)n0blk * MROWB;
    #pragma unroll
    for (int i = 0; i < 2; ++i) {
        const int idx = i * 256 + t;
        const int row = idx >> 3, c = idx & 7;
        if (!full && n0blk + row >= nNodes) continue;
        #pragma unroll
        for (int tab = 0; tab < 2; ++tab) {
            const uint8_t* lr = (tab ? ldsv : ldsu) + row * LROW;
            uint4 o;
            if (c < 7) {
                const uint32_t* wp = (const uint32_t*)(lr + 20 * c);
                const uint32_t b0 = wp[0], b1_ = wp[1], b2 = wp[2], b3 = wp[3], b4 = wp[4];
                o.x = (b0 & 63u) | (((b0 >> 8) & 63u) << 6) | (((b0 >> 16) & 63u) << 12)
                    | (((b0 >> 24) & 63u) << 18) | ((b1_ & 63u) << 24);
                o.y = ((b1_ >> 8) & 63u) | (((b1_ >> 16) & 63u) << 6) | (((b1_ >> 24) & 63u) << 12)
                    | ((b2 & 63u) << 18) | (((b2 >> 8) & 63u) << 24);
                o.z = ((b2 >> 16) & 63u) | (((b2 >> 24) & 63u) << 6) | ((b3 & 63u) << 12)
                    | (((b3 >> 8) & 63u) << 18) | (((b3 >> 16) & 63u) << 24);
                o.w = ((b3 >> 24) & 63u) | ((b4 & 63u) << 6) | (((b4 >> 8) & 63u) << 12)
                    | (((b4 >> 16) & 63u) << 18) | (((b4 >> 24) & 63u) << 24);
            } else {
                const uint32_t w0 = *(const uint32_t*)(lr + 140);
                const uint32_t w1 = *(const uint32_t*)(lr + 144);
                o.x = (w0 & 63u) | (((w0 >> 8) & 63u) << 6) | (((w0 >> 16) & 63u) << 12)
                    | (((w0 >> 24) & 63u) << 18) | ((w1 & 63u) << 24);
                o.y = *(const uint32_t*)(lr + 148);       // f32 scale
                o.z = 0u; o.w = 0u;
            }
            *(uint4*)((tab ? vg : ug) + 16 * idx) = o;
        }
    }
}

// ---------------------------------------------------------------------------
// edge_int6: r13 — 4 lanes per edge, FOUR edges per group, 64 edges per wave.
//   All 16 row-loads issued up front (16 outstanding uint4/lane -> 2x lines
//   in flight per wave vs r9) then processed per edge. Lane r reads u32s
//   [8r,8r+8) of u'[src] and v'[dst]; u32 = 5 vals at bits 6k; w2 zero-pad
//   past col 144 makes scale/pad words contribute 0. Scale = u32 idx 29 =
//   lane 3's 2nd uint4 .y; broadcast via shfl.
// ---------------------------------------------------------------------------
__global__ void __launch_bounds__(256)
edge_int6(const uint32_t* __restrict__ pairs,
          const uint8_t* __restrict__ u, const uint8_t* __restrict__ v,
          const float* __restrict__ w2p, const float* __restrict__ b2,
          float* __restrict__ out, int E)
{
    const int t = threadIdx.x;
    const int lane = t & 63;
    const int r = lane & 3;
    const int grp = lane >> 2;
    const int wid = blockIdx.x * (blockDim.x >> 6) + (t >> 6);
    const int base = wid * 64;
    const float bias2 = *b2;
    const int l3 = lane | 3;

    int ei[4]; bool ok[4];
    uint4 U[4][2], V[4][2];
    #pragma unroll
    for (int p = 0; p < 4; ++p) {
        ei[p] = base + p * 16 + grp;
        ok[p] = ei[p] < E;
        const uint32_t pr = pairs[ok[p] ? ei[p] : 0];
        const uint4* ua = (const uint4*)(u + (pr >> 16)     * (uint32_t)MROWB) + 2 * r;
        const uint4* va = (const uint4*)(v + (pr & 0xFFFFu) * (uint32_t)MROWB) + 2 * r;
        U[p][0] = ua[0]; U[p][1] = ua[1];
        V[p][0] = va[0]; V[p][1] = va[1];
    }

    const float* w2b = w2p + 40 * r;
    #pragma unroll
    for (int p = 0; p < 4; ++p) {
        const float su = __shfl(__uint_as_float(U[p][1].y), l3);
        const float sv = __shfl(__uint_as_float(V[p][1].y), l3);
        const float off = -32.f * (su + sv);
        const uint32_t uw[8] = {U[p][0].x, U[p][0].y, U[p][0].z, U[p][0].w,
                                U[p][1].x, U[p][1].y, U[p][1].z, U[p][1].w};
        const uint32_t vw[8] = {V[p][0].x, V[p][0].y, V[p][0].z, V[p][0].w,
                                V[p][1].x, V[p][1].y, V[p][1].z, V[p][1].w};
        float acc = 0.f;
        #pragma unroll
        for (int lw = 0; lw < 8; ++lw) {
            #pragma unroll
            for (int k = 0; k < 5; ++k) {
                const float w2v = w2b[5 * lw + k];
                const float uf = (float)((uw[lw] >> (6 * k)) & 63u);
                const float vf = (float)((vw[lw] >> (6 * k)) & 63u);
                float tv = fmaf(su, uf, fmaf(sv, vf, off));
                tv = fmaxf(tv, 0.f);
                acc = fmaf(tv, w2v, acc);
            }
        }
        acc += __shfl_xor(acc, 1);
        acc += __shfl_xor(acc, 2);
        if (r == 0 && ok[p]) out[ei[p]] = 1.f / (1.f + __expf(-(acc + bias2)));
    }
}

// ---------------------------------------------------------------------------
// fallback_kernel: direct per-edge compute (ws too small or nNodes > 65536)
// ---------------------------------------------------------------------------
__global__ void __launch_bounds__(256)
fallback_kernel(const void* __restrict__ eiv, const float* __restrict__ h,
                const float* __restrict__ cancer, const float* __restrict__ causal,
                const float* __restrict__ W1, const float* __restrict__ b1,
                const float* __restrict__ W2, const float* __restrict__ b2,
                float* __restrict__ out, int E)
{
    const int lane = threadIdx.x & 63;
    const int wpb  = blockDim.x >> 6;
    const int wid  = blockIdx.x * wpb + (threadIdx.x >> 6);
    const int nW   = gridDim.x * wpb;
    const uint32_t* p32 = (const uint32_t*)eiv;
    const uint32_t o = p32[1] | p32[3] | p32[5] | p32[7] | p32[9] | p32[11] | p32[13] | p32[15];
    const int is64 = (o == 0u);
    const long long* e64 = (const long long*)eiv;
    const int*       e32 = (const int*)eiv;
    const float bias2 = *b2;

    for (int e = wid; e < E; e += nW) {
        long long src, dst;
        if (is64) { src = e64[e]; dst = e64[(size_t)E + e]; }
        else      { src = e32[e]; dst = e32[(size_t)E + e]; }
        const float ci = causal[src], cj = causal[dst];
        float acc0 = 0.f, acc1 = 0.f, acc2 = 0.f;
        const int j0 = lane, j1 = lane + 64, j2 = lane + 128;
        for (int k = 0; k < 291; ++k) {
            float f;
            if      (k < 128) f = h[(size_t)src * 128 + k];
            else if (k < 256) f = h[(size_t)dst * 128 + (k - 128)];
            else if (k < 288) f = cancer[k - 256];
            else if (k == 288) f = ci;
            else if (k == 289) f = cj;
            else               f = ci - cj;
            const float* wr = W1 + (size_t)k * HID;
            acc0 = fmaf(f, wr[j0], acc0);
            acc1 = fmaf(f, wr[j1], acc1);
            if (j2 < HID) acc2 = fmaf(f, wr[j2], acc2);
        }
        float partial = fmaxf(acc0 + b1[j0], 0.f) * W2[j0]
                      + fmaxf(acc1 + b1[j1], 0.f) * W2[j1];
        if (j2 < HID) partial += fmaxf(acc2 + b1[j2], 0.f) * W2[j2];
        #pragma unroll
        for (int m = 32; m; m >>= 1) partial += __shfl_xor(partial, m, 64);
        if (lane == 0) out[e] = 1.f / (1.f + __expf(-(partial + bias2)));
    }
}

// ---------------------------------------------------------------------------
extern "C" void kernel_launch(void* const* d_in, const int* in_sizes, int n_in,
                              void* d_out, int out_size, void* d_ws, size_t ws_size,
                              hipStream_t stream)
{
    const float* h      = (const float*)d_in[0];
    const void*  ei     = d_in[1];
    const float* cancer = (const float*)d_in[2];
    const float* causal = (const float*)d_in[3];
    const float* W1     = (const float*)d_in[4];
    const float* b1     = (const float*)d_in[5];
    const float* W2     = (const float*)d_in[6];
    const float* b2     = (const float*)d_in[7];
    float* outp = (float*)d_out;

    const int nNodes = in_sizes[0] / EMBED;
    const int E      = in_sizes[1] / 2;

    // workspace layout
    const size_t WPB_OFF   = 8192;                      // 80 KB -> ends 90112
    const size_t PAIRS_OFF = 98304;
    const size_t pairsB    = ((size_t)E * 4 + 255) & ~(size_t)255;
    const size_t tabB      = (size_t)nNodes * MROWB;    // 6.4 MB each
    const size_t U_OFF     = PAIRS_OFF + pairsB;
    const size_t V_OFF     = (U_OFF + tabB + 255) & ~(size_t)255;
    const size_t need      = V_OFF + tabB;

    char* ws = (char*)d_ws;
    float* b1p  = (float*)(ws + 1024);
    float* wci  = (float*)(ws + 2048);
    float* wcj  = (float*)(ws + 3072);
    float* w2p  = (float*)(ws + 4096);
    short* Wpb  = (short*)(ws + WPB_OFF);

    if (ws_size >= need && nNodes <= 65536) {
        uint32_t* pairs = (uint32_t*)(ws + PAIRS_OFF);
        uint8_t*  u     = (uint8_t*)(ws + U_OFF);
        uint8_t*  v     = (uint8_t*)(ws + V_OFF);

        const int P = (E + 255) / 256;
        prep_fused<<<P + 161, 256, 0, stream>>>(cancer, W1, b1, W2, ei, E, P,
                                                b1p, wci, wcj, w2p, Wpb, pairs);
        proj_mfma<<<(nNodes + 63) / 64, 256, 0, stream>>>(h, Wpb, causal, b1p,
                                                          wci, wcj, u, v, nNodes);
        const int blocks = (E + 255) / 256;             // 64 edges/wave, 4 waves/block
        edge_int6<<<blocks, 256, 0, stream>>>(pairs, u, v, w2p, b2, outp, E);
    } else {
        fallback_kernel<<<2048, 256, 0, stream>>>(ei, h, cancer, causal, W1, b1, W2, b2,
                                                  outp, E);
    }
}

// Round 14
// 66.380 us; speedup vs baseline: 1.0576x; 1.0576x over previous
//
#include <hip/hip_runtime.h>
#include <hip/hip_bf16.h>
#include <stdint.h>

#define EMBED 128
#define HID 145
#define HSTR 160            // padded col count per table (MFMA tiles)
#define NTILE 20            // 320 output cols / 16
#define KCH 4               // 128 K / 32
#define MROWB 128           // int6 row: 32 u32 words, word widx=lane15*2+hf holds
                            // cols (hf*5+i)*16+lane15, i=0..4, 6 bits each (30 used)
#define HB2ROW 272          // bf16 h-staging row stride in bytes (256 + 16 pad)

typedef __attribute__((ext_vector_type(8))) short short8;
typedef __attribute__((ext_vector_type(4))) float f32x4;

__device__ __forceinline__ uint16_t f2bf(float f) {
    uint32_t x = __float_as_uint(f);
    x += 0x7FFFu + ((x >> 16) & 1u);          // round-to-nearest-even
    return (uint16_t)(x >> 16);
}
__device__ __forceinline__ short f2bf_cvt(float f) {
    union { __bf16 h; short s; } u_;
    u_.h = (__bf16)f;
    return u_.s;
}

// ---------------------------------------------------------------------------
// prep_fused: blocks [0,P): pack pairs[e]=(src<<16)|dst
//             blocks [P,P+160): pack W1 into bf16 B-fragment order (Wpb)
//             block P+160: fold cancer/b1/causal cols; w2q in permuted-word
//             order: w2q[widx*5+i] = W2[(hf*5+i)*16 + (widx>>1)], hf=widx&1
// ---------------------------------------------------------------------------
__global__ void __launch_bounds__(256)
prep_fused(const float* __restrict__ cancer, const float* __restrict__ W1,
           const float* __restrict__ b1, const float* __restrict__ W2,
           const void* __restrict__ eiv, int E, int P,
           float* __restrict__ b1p, float* __restrict__ wci,
           float* __restrict__ wcj, float* __restrict__ w2q,
           short* __restrict__ Wpb, uint32_t* __restrict__ pairs)
{
    const int t = threadIdx.x;
    const int b = blockIdx.x;
    if (b < P) {
        // int64 indices < 65536 => every odd 32-bit word is zero.
        const uint32_t* pw = (const uint32_t*)eiv;
        const uint32_t odd = pw[1] | pw[3] | pw[5] | pw[7] | pw[9] | pw[11] | pw[13] | pw[15];
        const int is64 = (odd == 0u);
        const int e = b * 256 + t;
        if (e < E) {
            uint32_t src, dst;
            if (is64) {
                const long long* e64 = (const long long*)eiv;
                src = (uint32_t)e64[e]; dst = (uint32_t)e64[(size_t)E + e];
            } else {
                const uint32_t* e32 = (const uint32_t*)eiv;
                src = e32[e];           dst = e32[(size_t)E + e];
            }
            pairs[e] = (src << 16) | (dst & 0xFFFFu);
        }
        return;
    }
    if (b < P + 160) {
        const int idx = (b - P) * 256 + t;            // < 40960
        const int reg  = idx & 7;
        const int lane = (idx >> 3) & 63;
        const int tl   = idx >> 9;                    // 0..79
        const int tt   = tl % NTILE;
        const int kc   = tl / NTILE;
        const int k    = kc * 32 + (lane >> 4) * 8 + reg;
        const int col  = tt * 16 + (lane & 15);
        float val = 0.f;
        if (col < HID)                             val = W1[(size_t)k * HID + col];
        else if (col >= HSTR && col < HSTR + HID)  val = W1[(size_t)(EMBED + k) * HID + (col - HSTR)];
        Wpb[idx] = (short)f2bf(val);
        return;
    }
    // smalls
    if (t < HSTR) {
        float bv = 0.f, a = 0.f, bb = 0.f;
        if (t < HID) {
            float s = b1[t];
            #pragma unroll
            for (int k = 0; k < 32; ++k)
                s = fmaf(cancer[k], W1[(size_t)(2 * EMBED + k) * HID + t], s);
            bv = s;
            a  = W1[(size_t)288 * HID + t] + W1[(size_t)290 * HID + t];  // c_i + diff
            bb = W1[(size_t)289 * HID + t] - W1[(size_t)290 * HID + t];  // c_j - diff
        }
        b1p[t] = bv; wci[t] = a; wcj[t] = bb;
        // w2q: permuted-word order
        const int widx = t / 5, i = t % 5;
        const int hf = widx & 1, l15 = widx >> 1;
        const int col = (hf * 5 + i) * 16 + l15;
        w2q[t] = (col < HID) ? W2[col] : 0.f;
    }
}

// ---------------------------------------------------------------------------
// proj_mfma (r14): r11 MFMA structure (64 nodes/block, wave w owns 5 tiles
//   x 4 node-groups, B-fragments reused 4x, A from bf16-staged LDS), but the
//   epilogue packs each thread's 5 quantized int6 values into ONE u32 in
//   registers and stores it directly to global word widx=lane15*2+hf — no
//   LDS byte staging, no repack pass, one barrier fewer. Per-row scales go
//   to separate uscl/vscl arrays (L2-resident; edge reads them as dwords).
// ---------------------------------------------------------------------------
__global__ void __launch_bounds__(256)
proj_mfma(const float* __restrict__ h, const short* __restrict__ Wpb,
          const float* __restrict__ causal, const float* __restrict__ b1p,
          const float* __restrict__ wci, const float* __restrict__ wcj,
          uint8_t* __restrict__ u, uint8_t* __restrict__ v,
          float* __restrict__ uscl, float* __restrict__ vscl, int nNodes)
{
    __shared__ __align__(16) uint8_t smem[64 * HB2ROW];     // 17408 B
    __shared__ float pmax[2][2][64];                        // [table][wave-half][row]

    const int t = threadIdx.x;
    const int lane = t & 63;
    const int w = t >> 6;
    const int lane15 = lane & 15, hi = lane >> 4;
    const int n0blk = blockIdx.x * 64;
    const bool full = (n0blk + 64 <= nNodes);

    // ---- stage h as bf16: 64 rows x 256 B, dense coalesced copies
    const float4* hsrc = (const float4*)(h + (size_t)n0blk * EMBED);
    if (full) {
        #pragma unroll
        for (int k = 0; k < 8; ++k) {
            const int f = k * 256 + t;                 // float4 idx 0..2047
            const float4 x = hsrc[f];
            const uint32_t lo = (uint32_t)(uint16_t)f2bf_cvt(x.x)
                              | ((uint32_t)(uint16_t)f2bf_cvt(x.y) << 16);
            const uint32_t hg = (uint32_t)(uint16_t)f2bf_cvt(x.z)
                              | ((uint32_t)(uint16_t)f2bf_cvt(x.w) << 16);
            *(uint2*)(smem + (f >> 5) * HB2ROW + (f & 31) * 8) = make_uint2(lo, hg);
        }
    } else {
        #pragma unroll
        for (int k = 0; k < 8; ++k) {
            const int f = k * 256 + t;
            const int row = f >> 5;
            float4 x = make_float4(0.f, 0.f, 0.f, 0.f);
            if (n0blk + row < nNodes) x = hsrc[f];
            const uint32_t lo = (uint32_t)(uint16_t)f2bf_cvt(x.x)
                              | ((uint32_t)(uint16_t)f2bf_cvt(x.y) << 16);
            const uint32_t hg = (uint32_t)(uint16_t)f2bf_cvt(x.z)
                              | ((uint32_t)(uint16_t)f2bf_cvt(x.w) << 16);
            *(uint2*)(smem + row * HB2ROW + (f & 31) * 8) = make_uint2(lo, hg);
        }
    }
    __syncthreads();

    // ---- MFMA: acc[group g][tile i], tile tt = 5w+i, nodes g*16+row-in-frag
    const int w5 = 5 * w;
    const uint8_t* habase = smem + lane15 * HB2ROW + hi * 16;

    f32x4 acc[4][5];
    #pragma unroll
    for (int g = 0; g < 4; ++g)
        #pragma unroll
        for (int i = 0; i < 5; ++i) acc[g][i] = (f32x4){0.f, 0.f, 0.f, 0.f};

    const short8* bp = (const short8*)Wpb;
    #pragma unroll
    for (int kc = 0; kc < KCH; ++kc) {
        short8 bfr[5];
        #pragma unroll
        for (int i = 0; i < 5; ++i)
            bfr[i] = bp[(kc * NTILE + w5 + i) * 64 + lane];
        #pragma unroll
        for (int g = 0; g < 4; ++g) {
            const short8 a = *(const short8*)(habase + g * 16 * HB2ROW + kc * 64);
            #pragma unroll
            for (int i = 0; i < 5; ++i)
                acc[g][i] = __builtin_amdgcn_mfma_f32_16x16x32_bf16(a, bfr[i], acc[g][i], 0, 0, 0);
        }
    }

    // ---- fold bias/causal terms (addB/addC hoisted per tile)
    const int tb = w >> 1, hf = w & 1;                  // table (0=u,1=v), half
    float addB[5], addC[5];
    #pragma unroll
    for (int i = 0; i < 5; ++i) {
        const int col = (w5 + i) * 16 + lane15;
        const int ccol = tb ? col - HSTR : col;
        addB[i] = tb ? 0.f : b1p[ccol];
        addC[i] = tb ? wcj[ccol] : wci[ccol];
    }
    #pragma unroll
    for (int g = 0; g < 4; ++g) {
        float cz[4];
        #pragma unroll
        for (int j = 0; j < 4; ++j) {
            const int n = n0blk + g * 16 + hi * 4 + j;
            cz[j] = (n < nNodes) ? causal[n] : 0.f;
        }
        #pragma unroll
        for (int i = 0; i < 5; ++i)
            #pragma unroll
            for (int j = 0; j < 4; ++j)
                acc[g][i][j] += fmaf(cz[j], addC[i], addB[i]);
    }

    // ---- partial per-row absmax over this wave's 5 tiles -> pmax
    #pragma unroll
    for (int g = 0; g < 4; ++g) {
        #pragma unroll
        for (int j = 0; j < 4; ++j) {
            float m = fmaxf(fmaxf(fmaxf(fabsf(acc[g][0][j]), fabsf(acc[g][1][j])),
                                  fmaxf(fabsf(acc[g][2][j]), fabsf(acc[g][3][j]))),
                            fabsf(acc[g][4][j]));
            #pragma unroll
            for (int mk = 1; mk < 16; mk <<= 1) m = fmaxf(m, __shfl_xor(m, mk));
            if (lane15 == 0) pmax[tb][hf][g * 16 + hi * 4 + j] = m;
        }
    }
    __syncthreads();   // pmax complete across both halves

    // ---- quantize + pack in registers -> direct global u32 stores
    uint32_t* tabw = (uint32_t*)(tb ? v : u);
    float* sclp = tb ? vscl : uscl;
    const int widx = lane15 * 2 + hf;
    #pragma unroll
    for (int g = 0; g < 4; ++g) {
        #pragma unroll
        for (int j = 0; j < 4; ++j) {
            const int row = g * 16 + hi * 4 + j;
            const int n = n0blk + row;
            if (full || n < nNodes) {
                const float mm = fmaxf(fmaxf(pmax[tb][0][row], pmax[tb][1][row]), 1e-20f);
                const float inv = 31.f / mm;
                uint32_t wd = 0;
                #pragma unroll
                for (int i = 0; i < 5; ++i) {
                    const uint32_t q = (uint32_t)(acc[g][i][j] * inv + 32.5f) & 63u;
                    wd |= q << (6 * i);
                }
                tabw[(size_t)n * 32 + widx] = wd;
                if (widx == 0) sclp[n] = mm * (1.f / 31.f);
            }
        }
    }
}

// ---------------------------------------------------------------------------
// edge_int6 (r11-best 32-edge/wave structure): 4 lanes per edge, 2 edges per
//   group. Lane r reads u32 words [8r,8r+8) (2 uint4) of u'[src] and
//   v'[dst]; each u32 = 5 vals at bits 6k; w2q permuted to match so the dot
//   is order-agnostic; pad cols decode to (32-32)*s x w2=0. Scales from the
//   L2-resident uscl/vscl arrays (plain dword loads, broadcast-coalesced).
// ---------------------------------------------------------------------------
__global__ void __launch_bounds__(256)
edge_int6(const uint32_t* __restrict__ pairs,
          const uint8_t* __restrict__ u, const uint8_t* __restrict__ v,
          const float* __restrict__ uscl, const float* __restrict__ vscl,
          const float* __restrict__ w2q, const float* __restrict__ b2,
          float* __restrict__ out, int E)
{
    const int t = threadIdx.x;
    const int lane = t & 63;
    const int r = lane & 3;
    const int grp = lane >> 2;
    const int wid = blockIdx.x * (blockDim.x >> 6) + (t >> 6);
    const int base = wid * 32;
    const int e0 = base + grp, e1 = base + 16 + grp;
    const bool ok0 = e0 < E, ok1 = e1 < E;
    const float bias2 = *b2;

    const uint32_t pr0 = pairs[ok0 ? e0 : 0];
    const uint32_t pr1 = pairs[ok1 ? e1 : 0];
    const uint32_t s0 = pr0 >> 16, d0 = pr0 & 0xFFFFu;
    const uint32_t s1 = pr1 >> 16, d1 = pr1 & 0xFFFFu;

    const uint4* ua = (const uint4*)(u + s0 * (uint32_t)MROWB) + 2 * r;
    const uint4* va = (const uint4*)(v + d0 * (uint32_t)MROWB) + 2 * r;
    const uint4* ub = (const uint4*)(u + s1 * (uint32_t)MROWB) + 2 * r;
    const uint4* vb = (const uint4*)(v + d1 * (uint32_t)MROWB) + 2 * r;
    const uint4 UA0 = ua[0], UA1 = ua[1];
    const uint4 VA0 = va[0], VA1 = va[1];
    const uint4 UB0 = ub[0], UB1 = ub[1];
    const uint4 VB0 = vb[0], VB1 = vb[1];

    const float su0 = uscl[s0], sv0 = vscl[d0];
    const float su1 = uscl[s1], sv1 = vscl[d1];
    const float off0 = -32.f * (su0 + sv0);
    const float off1 = -32.f * (su1 + sv1);

    const uint32_t uw0[8] = {UA0.x, UA0.y, UA0.z, UA0.w, UA1.x, UA1.y, UA1.z, UA1.w};
    const uint32_t vw0[8] = {VA0.x, VA0.y, VA0.z, VA0.w, VA1.x, VA1.y, VA1.z, VA1.w};
    const uint32_t uw1[8] = {UB0.x, UB0.y, UB0.z, UB0.w, UB1.x, UB1.y, UB1.z, UB1.w};
    const uint32_t vw1[8] = {VB0.x, VB0.y, VB0.z, VB0.w, VB1.x, VB1.y, VB1.z, VB1.w};

    const float* w2b = w2q + 40 * r;
    float acc0 = 0.f, acc1 = 0.f;
    #pragma unroll
    for (int lw = 0; lw < 8; ++lw) {
        #pragma unroll
        for (int k = 0; k < 5; ++k) {
            const float w2v = w2b[5 * lw + k];
            const float uf0 = (float)((uw0[lw] >> (6 * k)) & 63u);
            const float vf0 = (float)((vw0[lw] >> (6 * k)) & 63u);
            float tv0 = fmaf(su0, uf0, fmaf(sv0, vf0, off0));
            tv0 = fmaxf(tv0, 0.f);
            acc0 = fmaf(tv0, w2v, acc0);
            const float uf1 = (float)((uw1[lw] >> (6 * k)) & 63u);
            const float vf1 = (float)((vw1[lw] >> (6 * k)) & 63u);
            float tv1 = fmaf(su1, uf1, fmaf(sv1, vf1, off1));
            tv1 = fmaxf(tv1, 0.f);
            acc1 = fmaf(tv1, w2v, acc1);
        }
    }
    acc0 += __shfl_xor(acc0, 1);
    acc0 += __shfl_xor(acc0, 2);
    acc1 += __shfl_xor(acc1, 1);
    acc1 += __shfl_xor(acc1, 2);
    if (r == 0 && ok0) out[e0] = 1.f / (1.f + __expf(-(acc0 + bias2)));
    if (r == 0 && ok1) out[e1] = 1.f / (1.f + __expf(-(acc1 + bias2)));
}

// ---------------------------------------------------------------------------
// fallback_kernel: direct per-edge compute (ws too small or nNodes > 65536)
// ---------------------------------------------------------------------------
__global__ void __launch_bounds__(256)
fallback_kernel(const void* __restrict__ eiv, const float* __restrict__ h,
                const float* __restrict__ cancer, const float* __restrict__ causal,
                const float* __restrict__ W1, const float* __restrict__ b1,
                const float* __restrict__ W2, const float* __restrict__ b2,
                float* __restrict__ out, int E)
{
    const int lane = threadIdx.x & 63;
    const int wpb  = blockDim.x >> 6;
    const int wid  = blockIdx.x * wpb + (threadIdx.x >> 6);
    const int nW   = gridDim.x * wpb;
    const uint32_t* p32 = (const uint32_t*)eiv;
    const uint32_t o = p32[1] | p32[3] | p32[5] | p32[7] | p32[9] | p32[11] | p32[13] | p32[15];
    const int is64 = (o == 0u);
    const long long* e64 = (const long long*)eiv;
    const int*       e32 = (const int*)eiv;
    const float bias2 = *b2;

    for (int e = wid; e < E; e += nW) {
        long long src, dst;
        if (is64) { src = e64[e]; dst = e64[(size_t)E + e]; }
        else      { src = e32[e]; dst = e32[(size_t)E + e]; }
        const float ci = causal[src], cj = causal[dst];
        float acc0 = 0.f, acc1 = 0.f, acc2 = 0.f;
        const int j0 = lane, j1 = lane + 64, j2 = lane + 128;
        for (int k = 0; k < 291; ++k) {
            float f;
            if      (k < 128) f = h[(size_t)src * 128 + k];
            else if (k < 256) f = h[(size_t)dst * 128 + (k - 128)];
            else if (k < 288) f = cancer[k - 256];
            else if (k == 288) f = ci;
            else if (k == 289) f = cj;
            else               f = ci - cj;
            const float* wr = W1 + (size_t)k * HID;
            acc0 = fmaf(f, wr[j0], acc0);
            acc1 = fmaf(f, wr[j1], acc1);
            if (j2 < HID) acc2 = fmaf(f, wr[j2], acc2);
        }
        float partial = fmaxf(acc0 + b1[j0], 0.f) * W2[j0]
                      + fmaxf(acc1 + b1[j1], 0.f) * W2[j1];
        if (j2 < HID) partial += fmaxf(acc2 + b1[j2], 0.f) * W2[j2];
        #pragma unroll
        for (int m = 32; m; m >>= 1) partial += __shfl_xor(partial, m, 64);
        if (lane == 0) out[e] = 1.f / (1.f + __expf(-(partial + bias2)));
    }
}

// ---------------------------------------------------------------------------
extern "C" void kernel_launch(void* const* d_in, const int* in_sizes, int n_in,
                              void* d_out, int out_size, void* d_ws, size_t ws_size,
                              hipStream_t stream)
{
    const float* h      = (const float*)d_in[0];
    const void*  ei     = d_in[1];
    const float* cancer = (const float*)d_in[2];
    const float* causal = (const float*)d_in[3];
    const float* W1     = (const float*)d_in[4];
    const float* b1     = (const float*)d_in[5];
    const float* W2     = (const float*)d_in[6];
    const float* b2     = (const float*)d_in[7];
    float* outp = (float*)d_out;

    const int nNodes = in_sizes[0] / EMBED;
    const int E      = in_sizes[1] / 2;

    // workspace layout
    const size_t WPB_OFF   = 8192;                      // 80 KB -> ends 90112
    const size_t PAIRS_OFF = 98304;
    const size_t pairsB    = ((size_t)E * 4 + 255) & ~(size_t)255;
    const size_t sclB      = ((size_t)nNodes * 4 + 255) & ~(size_t)255;
    const size_t tabB      = (size_t)nNodes * MROWB;    // 6.4 MB each
    const size_t USCL_OFF  = PAIRS_OFF + pairsB;
    const size_t VSCL_OFF  = USCL_OFF + sclB;
    const size_t U_OFF     = VSCL_OFF + sclB;
    const size_t V_OFF     = (U_OFF + tabB + 255) & ~(size_t)255;
    const size_t need      = V_OFF + tabB;

    char* ws = (char*)d_ws;
    float* b1p  = (float*)(ws + 1024);
    float* wci  = (float*)(ws + 2048);
    float* wcj  = (float*)(ws + 3072);
    float* w2q  = (float*)(ws + 4096);
    short* Wpb  = (short*)(ws + WPB_OFF);

    if (ws_size >= need && nNodes <= 65536) {
        uint32_t* pairs = (uint32_t*)(ws + PAIRS_OFF);
        float*    uscl  = (float*)(ws + USCL_OFF);
        float*    vscl  = (float*)(ws + VSCL_OFF);
        uint8_t*  u     = (uint8_t*)(ws + U_OFF);
        uint8_t*  v     = (uint8_t*)(ws + V_OFF);

        const int P = (E + 255) / 256;
        prep_fused<<<P + 161, 256, 0, stream>>>(cancer, W1, b1, W2, ei, E, P,
                                                b1p, wci, wcj, w2q, Wpb, pairs);
        proj_mfma<<<(nNodes + 63) / 64, 256, 0, stream>>>(h, Wpb, causal, b1p,
                                                          wci, wcj, u, v,
                                                          uscl, vscl, nNodes);
        const int waves  = (E + 31) / 32;
        const int blocks = (waves + 3) / 4;
        edge_int6<<<blocks, 256, 0, stream>>>(pairs, u, v, uscl, vscl,
                                              w2q, b2, outp, E);
    } else {
        fallback_kernel<<<2048, 256, 0, stream>>>(ei, h, cancer, causal, W1, b1, W2, b2,
                                                  outp, E);
    }
}